// Round 3
// baseline (1370.593 us; speedup 1.0000x reference)
//
#include <hip/hip_runtime.h>
#include <cstdint>
#include <cstddef>

#define NN 262144
#define EE 1048576
#define BB 512
#define SEG 512

// ---------------- Threefry-2x32 (exact JAX replica) ----------------
__device__ __forceinline__ unsigned rotl32(unsigned x, int r) {
    return (x << r) | (x >> (32 - r));
}

__device__ __forceinline__ void tf2x32(unsigned k0, unsigned k1, unsigned x0, unsigned x1,
                                       unsigned& o0, unsigned& o1) {
    unsigned ks[3] = {k0, k1, k0 ^ k1 ^ 0x1BD11BDAu};
    x0 += ks[0]; x1 += ks[1];
    const int R0[4] = {13, 15, 26, 6};
    const int R1[4] = {17, 29, 16, 24};
#pragma unroll
    for (int i = 0; i < 5; ++i) {
        const int* R = (i & 1) ? R1 : R0;
#pragma unroll
        for (int j = 0; j < 4; ++j) {
            x0 += x1;
            x1 = rotl32(x1, R[j]);
            x1 ^= x0;
        }
        x0 += ks[(i + 1) % 3];
        x1 += ks[(i + 2) % 3] + (unsigned)(i + 1);
    }
    o0 = x0; o1 = x1;
}

// uniform(key=(0,42), (N,), minval=1e-6, maxval=1-1e-6) at flat index idx
__device__ __forceinline__ float unif_loc(unsigned idx) {
    unsigned j = idx & (NN / 2 - 1);
    unsigned half = idx >> 17;   // N/2 = 2^17
    unsigned o0, o1;
    tf2x32(0u, 42u, j, j + (unsigned)(NN / 2), o0, o1);
    unsigned bits = half ? o1 : o0;
    float f = __uint_as_float((bits >> 9) | 0x3F800000u) - 1.0f;
    const float minv = 1e-6f;
    const float maxv = 1.0f - 1e-6f;
    const float span = maxv - minv;
    return fmaxf(minv, __fadd_rn(__fmul_rn(f, span), minv));
}

// ---------------- CSR build ----------------
__global__ void csr_count(const int* __restrict__ dst, int* __restrict__ counts, int E) {
    int i = blockIdx.x * 256 + threadIdx.x;
    if (i < E) atomicAdd(&counts[dst[i]], 1);
}

__global__ void scan512(const int* __restrict__ in, int* __restrict__ outExcl, int* __restrict__ bsum) {
    __shared__ int s[512];
    int b = blockIdx.x, tid = threadIdx.x;
    int v = in[(size_t)b * 512 + tid];
    s[tid] = v;
    __syncthreads();
    for (int d = 1; d < 512; d <<= 1) {
        int add = (tid >= d) ? s[tid - d] : 0;
        __syncthreads();
        s[tid] += add;
        __syncthreads();
    }
    outExcl[(size_t)b * 512 + tid] = s[tid] - v;  // exclusive
    if (tid == 511) bsum[b] = s[511];
}

__global__ void scan_fix(int* __restrict__ offs, const int* __restrict__ bbase,
                         int* __restrict__ cursor, int N, int E) {
    int gid = blockIdx.x * 512 + threadIdx.x;
    int v = offs[gid] + bbase[blockIdx.x];
    offs[gid] = v;
    cursor[gid] = v;
    if (gid == 0) offs[N] = E;
}

__global__ void csr_fill(const int* __restrict__ dst, int* __restrict__ cursor,
                         int* __restrict__ perm, int E) {
    int i = blockIdx.x * 256 + threadIdx.x;
    if (i < E) {
        int p = atomicAdd(&cursor[dst[i]], 1);
        perm[p] = i;
    }
}

// ---------------- Layer 0: aggregate (dim 8), thread per node ----------------
__global__ void agg_l0(const float* __restrict__ x, const float* __restrict__ ea,
                       const int* __restrict__ src, const int* __restrict__ offs,
                       const int* __restrict__ perm,
                       const float* __restrict__ We0, const float* __restrict__ be0,
                       float* __restrict__ out) {
    __shared__ float Ws[32];
    __shared__ float bs[8];
    int tid = threadIdx.x;
    if (tid < 32) Ws[tid] = We0[tid];
    if (tid < 8) bs[tid] = be0[tid];
    __syncthreads();
    int n = blockIdx.x * 256 + tid;
    float a[8] = {0.f, 0.f, 0.f, 0.f, 0.f, 0.f, 0.f, 0.f};
    int pb = offs[n], pe = offs[n + 1];
    for (int p = pb; p < pe; ++p) {
        int e = perm[p];
        int s = src[e];
        float4 ev = *(const float4*)(ea + (size_t)e * 4);
        float4 xa = *(const float4*)(x + (size_t)s * 8);
        float4 xb = *(const float4*)(x + (size_t)s * 8 + 4);
        float xs[8] = {xa.x, xa.y, xa.z, xa.w, xb.x, xb.y, xb.z, xb.w};
#pragma unroll
        for (int j2 = 0; j2 < 8; ++j2) {
            float m = xs[j2] + bs[j2] + ev.x * Ws[j2] + ev.y * Ws[8 + j2] +
                      ev.z * Ws[16 + j2] + ev.w * Ws[24 + j2];
            a[j2] += fmaxf(m, 0.f);
        }
    }
    float4 o0 = {a[0], a[1], a[2], a[3]};
    float4 o1 = {a[4], a[5], a[6], a[7]};
    *(float4*)(out + (size_t)n * 8) = o0;
    *(float4*)(out + (size_t)n * 8 + 4) = o1;
}

// ---------------- Layer 0: update h1 = relu((x+agg0)@W0 + b0) ----------------
__global__ void update_l0(const float* __restrict__ x, const float* __restrict__ agg0,
                          const float* __restrict__ W0, const float* __restrict__ b0,
                          float* __restrict__ h1) {
    __shared__ float Ws[8 * 128];
    __shared__ float bs[128];
    __shared__ float ts[2][8];
    int tid = threadIdx.x;
#pragma unroll
    for (int i = tid; i < 1024; i += 256) Ws[i] = W0[i];
    if (tid < 128) bs[tid] = b0[tid];
    int sub = tid >> 7;
    int c = tid & 127;
    int node = blockIdx.x * 2 + sub;
    if (c < 8) ts[sub][c] = x[(size_t)node * 8 + c] + agg0[(size_t)node * 8 + c];
    __syncthreads();
    float acc = bs[c];
#pragma unroll
    for (int k = 0; k < 8; ++k) acc = fmaf(ts[sub][k], Ws[k * 128 + c], acc);
    h1[(size_t)node * 128 + c] = fmaxf(acc, 0.f);
}

// ---------------- Layers 1,2: fused msg+aggregate, wave per node ----------------
__global__ void agg_l(const float* __restrict__ h, const float* __restrict__ ea,
                      const int* __restrict__ src, const int* __restrict__ offs,
                      const int* __restrict__ perm,
                      const float* __restrict__ We, const float* __restrict__ be,
                      float* __restrict__ out) {
    __shared__ float Ws[512];
    __shared__ float bs[128];
    int tid = threadIdx.x;
    for (int i = tid; i < 512; i += 256) Ws[i] = We[i];
    if (tid < 128) bs[tid] = be[tid];
    __syncthreads();
    int node = blockIdx.x * 4 + (tid >> 6);
    node = __builtin_amdgcn_readfirstlane(node);
    int lane = tid & 63;
    float b0v = bs[lane], b1v = bs[64 + lane];
    float w00 = Ws[lane],      w01 = Ws[128 + lane], w02 = Ws[256 + lane], w03 = Ws[384 + lane];
    float w10 = Ws[64 + lane], w11 = Ws[192 + lane], w12 = Ws[320 + lane], w13 = Ws[448 + lane];
    float a0 = 0.f, a1 = 0.f;
    int pb = offs[node], pe = offs[node + 1];
    for (int p = pb; p < pe; ++p) {
        int e = perm[p];
        int s = src[e];
        float4 ev = *(const float4*)(ea + (size_t)e * 4);
        float hv0 = h[(size_t)s * 128 + lane];
        float hv1 = h[(size_t)s * 128 + 64 + lane];
        float m0 = hv0 + b0v + ev.x * w00 + ev.y * w01 + ev.z * w02 + ev.w * w03;
        float m1 = hv1 + b1v + ev.x * w10 + ev.y * w11 + ev.z * w12 + ev.w * w13;
        a0 += fmaxf(m0, 0.f);
        a1 += fmaxf(m1, 0.f);
    }
    out[(size_t)node * 128 + lane] = a0;
    out[(size_t)node * 128 + 64 + lane] = a1;
}

// ---------------- GEMM: out = relu((P [+ Q]) @ W + bias), [N,128]x[128,128] ----------------
// In-place over P or Q is safe: block b reads/writes only rows 32b..32b+31,
// and all its reads complete (staged to LDS) before its writes.
#define ACCROW(m, a)                                                                         \
    acc[m][0] = fmaf(a.x, w0.x, fmaf(a.y, w1.x, fmaf(a.z, w2.x, fmaf(a.w, w3.x, acc[m][0])))); \
    acc[m][1] = fmaf(a.x, w0.y, fmaf(a.y, w1.y, fmaf(a.z, w2.y, fmaf(a.w, w3.y, acc[m][1])))); \
    acc[m][2] = fmaf(a.x, w0.z, fmaf(a.y, w1.z, fmaf(a.z, w2.z, fmaf(a.w, w3.z, acc[m][2])))); \
    acc[m][3] = fmaf(a.x, w0.w, fmaf(a.y, w1.w, fmaf(a.z, w2.w, fmaf(a.w, w3.w, acc[m][3]))));

__global__ __launch_bounds__(256) void gemm_k(const float* __restrict__ P, const float* Q,
                                              const float* __restrict__ W,
                                              const float* __restrict__ bias,
                                              float* out) {
    __shared__ float Ws[64 * 128];  // one 64-row half of W (32 KB)
    __shared__ float As[32 * 128];  // A tile (16 KB)
    int tid = threadIdx.x;
    int r0 = blockIdx.x * 32;
    // stage A tile = P (+ Q), coalesced float4
#pragma unroll
    for (int i = 0; i < 4; ++i) {
        int f = tid + 256 * i;       // 0..1023
        int r = f >> 5;              // 0..31
        int k4 = f & 31;             // 0..31
        size_t g = (size_t)(r0 + r) * 128 + 4 * k4;
        float4 pv = *(const float4*)(P + g);
        if (Q) {
            float4 qv = *(const float4*)(Q + g);
            pv.x += qv.x; pv.y += qv.y; pv.z += qv.z; pv.w += qv.w;
        }
        *(float4*)(As + (size_t)r * 128 + 4 * k4) = pv;
    }
    int cx = tid & 31;   // cols 4cx..4cx+3
    int ry = tid >> 5;   // rows 4ry..4ry+3
    float acc[4][4] = {};
    for (int half = 0; half < 2; ++half) {
        __syncthreads();  // A staged / previous half consumed
        const float4* Wg = (const float4*)(W + (size_t)half * 64 * 128);
#pragma unroll
        for (int i = 0; i < 8; ++i) ((float4*)Ws)[tid + 256 * i] = Wg[tid + 256 * i];
        __syncthreads();
        int kbase = 64 * half;
#pragma unroll 4
        for (int kk = 0; kk < 16; ++kk) {
            int k0 = 4 * kk;
            int ka = kbase + k0;
            float4 w0 = *(const float4*)(Ws + (size_t)(k0 + 0) * 128 + 4 * cx);
            float4 w1 = *(const float4*)(Ws + (size_t)(k0 + 1) * 128 + 4 * cx);
            float4 w2 = *(const float4*)(Ws + (size_t)(k0 + 2) * 128 + 4 * cx);
            float4 w3 = *(const float4*)(Ws + (size_t)(k0 + 3) * 128 + 4 * cx);
            float4 a0 = *(const float4*)(As + (size_t)(4 * ry + 0) * 128 + ka);
            float4 a1 = *(const float4*)(As + (size_t)(4 * ry + 1) * 128 + ka);
            float4 a2 = *(const float4*)(As + (size_t)(4 * ry + 2) * 128 + ka);
            float4 a3 = *(const float4*)(As + (size_t)(4 * ry + 3) * 128 + ka);
            ACCROW(0, a0)
            ACCROW(1, a1)
            ACCROW(2, a2)
            ACCROW(3, a3)
        }
    }
    float4 bv = *(const float4*)(bias + 4 * cx);
    float bb[4] = {bv.x, bv.y, bv.z, bv.w};
#pragma unroll
    for (int m = 0; m < 4; ++m) {
        float4 o;
        o.x = fmaxf(acc[m][0] + bb[0], 0.f);
        o.y = fmaxf(acc[m][1] + bb[1], 0.f);
        o.z = fmaxf(acc[m][2] + bb[2], 0.f);
        o.w = fmaxf(acc[m][3] + bb[3], 0.f);
        *(float4*)(out + (size_t)(r0 + 4 * ry + m) * 128 + 4 * cx) = o;
    }
}

// ---------------- loc logits: L[i] = dot(Hd[i], laW2) + lab2 (wave per node) ----------------
__global__ void loc_logit(const float* __restrict__ Hd, const float* __restrict__ laW2,
                          const float* __restrict__ lab2, float* __restrict__ L) {
    __shared__ float w2s[128];
    int tid = threadIdx.x;
    if (tid < 128) w2s[tid] = laW2[tid];
    __syncthreads();
    int wave = blockIdx.x * 4 + (tid >> 6);
    int lane = tid & 63;
    float v = Hd[(size_t)wave * 128 + lane] * w2s[lane] +
              Hd[(size_t)wave * 128 + 64 + lane] * w2s[64 + lane];
#pragma unroll
    for (int off = 32; off > 0; off >>= 1) v += __shfl_down(v, off, 64);
    if (lane == 0) L[wave] = v + lab2[0];
}

// ---------------- per-graph softmax + Gumbel-max sampling ----------------
__global__ void sample_k(const float* __restrict__ L, float* __restrict__ ob,
                         int* __restrict__ locInt) {
    int g = blockIdx.x, tid = threadIdx.x;  // 256 threads, 512 nodes
    __shared__ float sh[512];
    __shared__ float rb[256];
    __shared__ int ib[256];
    float l0 = L[g * 512 + tid];
    float l1 = L[g * 512 + 256 + tid];
    // --- max(logits)
    rb[tid] = fmaxf(l0, l1);
    __syncthreads();
    for (int s2 = 128; s2 > 0; s2 >>= 1) {
        if (tid < s2) rb[tid] = fmaxf(rb[tid], rb[tid + s2]);
        __syncthreads();
    }
    float mx = rb[0];
    __syncthreads();
    float s0 = l0 - mx, s1 = l1 - mx;
    sh[tid] = s0; sh[256 + tid] = s1;
    float e0 = expf(s0), e1 = expf(s1);
    // --- denom
    rb[tid] = e0 + e1;
    __syncthreads();
    for (int s2 = 128; s2 > 0; s2 >>= 1) {
        if (tid < s2) rb[tid] += rb[tid + s2];
        __syncthreads();
    }
    float denom = rb[0];
    __syncthreads();
    // --- sum2 = sum exp(sh)*sh
    rb[tid] = e0 * s0 + e1 * s1;
    __syncthreads();
    for (int s2 = 128; s2 > 0; s2 >>= 1) {
        if (tid < s2) rb[tid] += rb[tid + s2];
        __syncthreads();
    }
    float sum2 = rb[0];
    __syncthreads();
    // --- Gumbel perturbation (exact JAX bits)
    unsigned i0 = (unsigned)(g * 512 + tid);
    unsigned i1 = i0 + 256u;
    float p0 = l0 - logf(-logf(unif_loc(i0)));
    float p1 = l1 - logf(-logf(unif_loc(i1)));
    rb[tid] = fmaxf(p0, p1);
    __syncthreads();
    for (int s2 = 128; s2 > 0; s2 >>= 1) {
        if (tid < s2) rb[tid] = fmaxf(rb[tid], rb[tid + s2]);
        __syncthreads();
    }
    float pmax = rb[0];
    __syncthreads();
    int c0 = (p0 >= pmax) ? tid : 0x7FFFFFFF;
    int c1 = (p1 >= pmax) ? (tid + 256) : 0x7FFFFFFF;
    ib[tid] = min(c0, c1);
    __syncthreads();
    for (int s2 = 128; s2 > 0; s2 >>= 1) {
        if (tid < s2) ib[tid] = min(ib[tid], ib[tid + s2]);
        __syncthreads();
    }
    if (tid == 0) {
        int li = ib[0];
        float logD = logf(denom);
        ob[g] = (float)(g * 512 + li);          // locations
        ob[1024 + g] = sh[li] - logD;           // loc_log_probs
        ob[2048 + g] = logD - sum2 / denom;     // loc_entropy
        locInt[g] = g * 512 + li;
    }
}

// ---------------- pooled = segment_sum(emb) ----------------
__global__ void pool_k(const float* __restrict__ emb, float* __restrict__ pooled) {
    int g = blockIdx.x, tid = threadIdx.x;  // 512 threads
    int c = tid & 127, rg = tid >> 7;
    __shared__ float sh[512];
    float s0 = 0.f, s1 = 0.f, s2 = 0.f, s3 = 0.f;
    const float* base = emb + ((size_t)g * 512 + (size_t)rg * 128) * 128 + c;
    for (int n = 0; n < 128; n += 4) {
        s0 += base[(size_t)(n + 0) * 128];
        s1 += base[(size_t)(n + 1) * 128];
        s2 += base[(size_t)(n + 2) * 128];
        s3 += base[(size_t)(n + 3) * 128];
    }
    sh[tid] = (s0 + s1) + (s2 + s3);
    __syncthreads();
    if (rg == 0) pooled[g * 128 + c] = sh[c] + sh[128 + c] + sh[256 + c] + sh[384 + c];
}

// ---------------- heads: mutation actor + both critics ----------------
__global__ void heads_k(const float* __restrict__ emb, const float* __restrict__ pooled,
                        const int* __restrict__ locInt,
                        const float* __restrict__ maW1, const float* __restrict__ mab1,
                        const float* __restrict__ maW2, const float* __restrict__ mab2,
                        const float* __restrict__ lcW1, const float* __restrict__ lcb1,
                        const float* __restrict__ lcW2, const float* __restrict__ lcb2,
                        const float* __restrict__ mcW1, const float* __restrict__ mcb1,
                        const float* __restrict__ mcW2, const float* __restrict__ mcb2,
                        float* __restrict__ ob) {
    int g = blockIdx.x, tid = threadIdx.x;  // 128 threads
    __shared__ float sel[128], pl[128];
    __shared__ float red[4][128];
    __shared__ float red1[128];
    __shared__ float mcv_sh;
    sel[tid] = emb[(size_t)locInt[g] * 128 + tid];
    pl[tid] = pooled[g * 128 + tid];
    __syncthreads();
    // mutation actor hidden
    float h = mab1[tid];
    for (int k = 0; k < 128; ++k) h = fmaf(sel[k], maW1[k * 128 + tid], h);
    h = fmaxf(h, 0.f);
    red[0][tid] = h * maW2[tid * 4 + 0];
    red[1][tid] = h * maW2[tid * 4 + 1];
    red[2][tid] = h * maW2[tid * 4 + 2];
    red[3][tid] = h * maW2[tid * 4 + 3];
    __syncthreads();
    for (int s2 = 64; s2 > 0; s2 >>= 1) {
        if (tid < s2) {
            red[0][tid] += red[0][tid + s2];
            red[1][tid] += red[1][tid + s2];
            red[2][tid] += red[2][tid + s2];
            red[3][tid] += red[3][tid + s2];
        }
        __syncthreads();
    }
    // mutation critic
    float h2 = mcb1[tid];
    for (int k = 0; k < 128; ++k) h2 = fmaf(sel[k], mcW1[k * 128 + tid], h2);
    h2 = fmaxf(h2, 0.f);
    red1[tid] = h2 * mcW2[tid];
    __syncthreads();
    for (int s2 = 64; s2 > 0; s2 >>= 1) {
        if (tid < s2) red1[tid] += red1[tid + s2];
        __syncthreads();
    }
    if (tid == 0) mcv_sh = red1[0] + mcb2[0];
    __syncthreads();
    // location critic (on pooled)
    float h3 = lcb1[tid];
    for (int k = 0; k < 128; ++k) h3 = fmaf(pl[k], lcW1[k * 128 + tid], h3);
    h3 = fmaxf(h3, 0.f);
    red1[tid] = h3 * lcW2[tid];
    __syncthreads();
    for (int s2 = 64; s2 > 0; s2 >>= 1) {
        if (tid < s2) red1[tid] += red1[tid + s2];
        __syncthreads();
    }
    if (tid == 0) {
        float lcv = red1[0] + lcb2[0];
        float lg[4];
#pragma unroll
        for (int c = 0; c < 4; ++c) lg[c] = red[c][0] + mab2[c];
        // folded key = threefry((0,42), (0,1))
        unsigned fk0, fk1;
        tf2x32(0u, 42u, 0u, 1u, fk0, fk1);
        float gmb[4];
#pragma unroll
        for (int c = 0; c < 4; ++c) {
            unsigned m = (unsigned)(g * 4 + c);
            unsigned j = m & 1023u;
            unsigned halfb = m >> 10;
            unsigned o0, o1;
            tf2x32(fk0, fk1, j, j + 1024u, o0, o1);
            unsigned bits = halfb ? o1 : o0;
            float f = __uint_as_float((bits >> 9) | 0x3F800000u) - 1.0f;
            const float tiny = 1.17549435e-38f;
            float u = fmaxf(tiny, __fadd_rn(__fmul_rn(f, 1.0f), tiny));
            gmb[c] = -logf(-logf(u));
        }
        int best = 0;
        float bz = gmb[0] + lg[0];
#pragma unroll
        for (int c = 1; c < 4; ++c) {
            float z = gmb[c] + lg[c];
            if (z > bz) { bz = z; best = c; }
        }
        float M = fmaxf(fmaxf(lg[0], lg[1]), fmaxf(lg[2], lg[3]));
        float se = 0.f;
#pragma unroll
        for (int c = 0; c < 4; ++c) se += expf(lg[c] - M);
        float lse = M + logf(se);
        float ent = 0.f;
#pragma unroll
        for (int c = 0; c < 4; ++c) {
            float lp = lg[c] - lse;
            ent -= expf(lp) * lp;
        }
        ob[512 + g] = (float)best;        // mutations
        ob[1536 + g] = lg[best] - lse;    // mut_log_probs
        ob[2560 + g] = ent;               // mut_entropy
        ob[3072 + g] = lcv;               // loc_values
        ob[3584 + g] = mcv_sh;            // mut_values
    }
}

// ---------------- launch ----------------
extern "C" void kernel_launch(void* const* d_in, const int* in_sizes, int n_in,
                              void* d_out, int out_size, void* d_ws, size_t ws_size,
                              hipStream_t stream) {
    const float* x   = (const float*)d_in[0];
    const int* ei    = (const int*)d_in[1];
    const float* ea  = (const float*)d_in[2];
    const float* We0 = (const float*)d_in[5];
    const float* be0 = (const float*)d_in[6];
    const float* W0  = (const float*)d_in[7];
    const float* b0  = (const float*)d_in[8];
    const float* We1 = (const float*)d_in[9];
    const float* be1 = (const float*)d_in[10];
    const float* W1  = (const float*)d_in[11];
    const float* b1  = (const float*)d_in[12];
    const float* We2 = (const float*)d_in[13];
    const float* be2 = (const float*)d_in[14];
    const float* W2  = (const float*)d_in[15];
    const float* b2  = (const float*)d_in[16];
    const float* laW1 = (const float*)d_in[17];
    const float* lab1 = (const float*)d_in[18];
    const float* laW2 = (const float*)d_in[19];
    const float* lab2 = (const float*)d_in[20];
    const float* maW1 = (const float*)d_in[21];
    const float* mab1 = (const float*)d_in[22];
    const float* maW2 = (const float*)d_in[23];
    const float* mab2 = (const float*)d_in[24];
    const float* lcW1 = (const float*)d_in[25];
    const float* lcb1 = (const float*)d_in[26];
    const float* lcW2 = (const float*)d_in[27];
    const float* lcb2 = (const float*)d_in[28];
    const float* mcW1 = (const float*)d_in[29];
    const float* mcb1 = (const float*)d_in[30];
    const float* mcW2 = (const float*)d_in[31];
    const float* mcb2 = (const float*)d_in[32];

    float* out = (float*)d_out;
    char* ws = (char*)d_ws;
    size_t off = 0;
    auto alloc = [&](size_t bytes) -> void* {
        void* p = ws + off;
        off += (bytes + 255) & ~(size_t)255;
        return p;
    };
    // ONE big ping-pong buffer in ws; the other is the emb region of d_out.
    float* U    = (float*)alloc((size_t)NN * 128 * 4);  // 128 MB
    float* Lg   = (float*)alloc((size_t)NN * 4);        // 1 MB
    int* counts = (int*)alloc((size_t)NN * 4);
    int* offs   = (int*)alloc((size_t)(NN + 1) * 4);
    int* cursor = (int*)alloc((size_t)NN * 4);
    int* perm   = (int*)alloc((size_t)EE * 4);          // 4 MB
    int* bsum   = (int*)alloc(512 * 4);
    int* bbase  = (int*)alloc(512 * 4);
    int* bscr   = (int*)alloc(512 * 4);
    float* pooled = (float*)alloc((size_t)BB * 128 * 4);
    int* locInt = (int*)alloc((size_t)BB * 4);
    // total ws: ~142 MB

    const int* src = ei;
    const int* dstA = ei + EE;
    float* V = out + 4096;        // emb region of d_out, used as ping-pong buffer
    float* agg0 = U;              // aliases U; consumed before U is reused

    // CSR by destination (fixed across layers)
    hipMemsetAsync(counts, 0, (size_t)NN * 4, stream);
    csr_count<<<EE / 256, 256, 0, stream>>>(dstA, counts, EE);
    scan512<<<NN / 512, 512, 0, stream>>>(counts, offs, bsum);
    scan512<<<1, 512, 0, stream>>>(bsum, bbase, bscr);
    scan_fix<<<NN / 512, 512, 0, stream>>>(offs, bbase, cursor, NN, EE);
    csr_fill<<<EE / 256, 256, 0, stream>>>(dstA, cursor, perm, EE);

    // GNN layers (ping-pong: V=d_out emb region, U=ws)
    agg_l0<<<NN / 256, 256, 0, stream>>>(x, ea, src, offs, perm, We0, be0, agg0);
    update_l0<<<NN / 2, 256, 0, stream>>>(x, agg0, W0, b0, V);            // h1 -> V
    agg_l<<<NN / 4, 256, 0, stream>>>(V, ea, src, offs, perm, We1, be1, U); // agg1 -> U
    gemm_k<<<NN / 32, 256, 0, stream>>>(V, U, W1, b1, U);                 // h2 -> U (in-place over Q)
    agg_l<<<NN / 4, 256, 0, stream>>>(U, ea, src, offs, perm, We2, be2, V); // agg2 -> V
    gemm_k<<<NN / 32, 256, 0, stream>>>(U, V, W2, b2, V);                 // emb -> V (d_out)

    // location actor
    gemm_k<<<NN / 32, 256, 0, stream>>>(V, nullptr, laW1, lab1, U);       // Hd -> U
    loc_logit<<<NN / 4, 256, 0, stream>>>(U, laW2, lab2, Lg);
    sample_k<<<BB, 256, 0, stream>>>(Lg, out, locInt);

    // pooling + heads
    pool_k<<<BB, 512, 0, stream>>>(V, pooled);
    heads_k<<<BB, 128, 0, stream>>>(V, pooled, locInt, maW1, mab1, maW2, mab2,
                                    lcW1, lcb1, lcW2, lcb2, mcW1, mcb1, mcW2, mcb2, out);
}

// Round 4
// 1125.257 us; speedup vs baseline: 1.2180x; 1.2180x over previous
//
#include <hip/hip_runtime.h>
#include <cstdint>
#include <cstddef>

#define NN 262144
#define EE 1048576
#define BB 512
#define SEG 512

// ---------------- Threefry-2x32 (exact JAX replica) ----------------
__device__ __forceinline__ unsigned rotl32(unsigned x, int r) {
    return (x << r) | (x >> (32 - r));
}

__device__ __forceinline__ void tf2x32(unsigned k0, unsigned k1, unsigned x0, unsigned x1,
                                       unsigned& o0, unsigned& o1) {
    unsigned ks[3] = {k0, k1, k0 ^ k1 ^ 0x1BD11BDAu};
    x0 += ks[0]; x1 += ks[1];
    const int R0[4] = {13, 15, 26, 6};
    const int R1[4] = {17, 29, 16, 24};
#pragma unroll
    for (int i = 0; i < 5; ++i) {
        const int* R = (i & 1) ? R1 : R0;
#pragma unroll
        for (int j = 0; j < 4; ++j) {
            x0 += x1;
            x1 = rotl32(x1, R[j]);
            x1 ^= x0;
        }
        x0 += ks[(i + 1) % 3];
        x1 += ks[(i + 2) % 3] + (unsigned)(i + 1);
    }
    o0 = x0; o1 = x1;
}

// uniform(key=(0,42), (N,), minval=1e-6, maxval=1-1e-6) at flat index idx
__device__ __forceinline__ float unif_loc(unsigned idx) {
    unsigned j = idx & (NN / 2 - 1);
    unsigned half = idx >> 17;   // N/2 = 2^17
    unsigned o0, o1;
    tf2x32(0u, 42u, j, j + (unsigned)(NN / 2), o0, o1);
    unsigned bits = half ? o1 : o0;
    float f = __uint_as_float((bits >> 9) | 0x3F800000u) - 1.0f;
    const float minv = 1e-6f;
    const float maxv = 1.0f - 1e-6f;
    const float span = maxv - minv;
    return fmaxf(minv, __fadd_rn(__fmul_rn(f, span), minv));
}

// ---------------- CSR build ----------------
__global__ void csr_count(const int* __restrict__ dst, int* __restrict__ counts, int E) {
    int i = blockIdx.x * 256 + threadIdx.x;
    if (i < E) atomicAdd(&counts[dst[i]], 1);
}

__global__ void scan512(const int* __restrict__ in, int* __restrict__ outExcl, int* __restrict__ bsum) {
    __shared__ int s[512];
    int b = blockIdx.x, tid = threadIdx.x;
    int v = in[(size_t)b * 512 + tid];
    s[tid] = v;
    __syncthreads();
    for (int d = 1; d < 512; d <<= 1) {
        int add = (tid >= d) ? s[tid - d] : 0;
        __syncthreads();
        s[tid] += add;
        __syncthreads();
    }
    outExcl[(size_t)b * 512 + tid] = s[tid] - v;  // exclusive
    if (tid == 511) bsum[b] = s[511];
}

__global__ void scan_fix(int* __restrict__ offs, const int* __restrict__ bbase,
                         int* __restrict__ cursor, int N, int E) {
    int gid = blockIdx.x * 512 + threadIdx.x;
    int v = offs[gid] + bbase[blockIdx.x];
    offs[gid] = v;
    cursor[gid] = v;
    if (gid == 0) offs[N] = E;
}

// scatter edges into dst-sorted order: ssrc[p]=src[i], sea[p]=ea[i]
__global__ void csr_fill(const int* __restrict__ dst, const int* __restrict__ src,
                         const float4* __restrict__ ea, int* __restrict__ cursor,
                         int* __restrict__ ssrc, float4* __restrict__ sea, int E) {
    int i = blockIdx.x * 256 + threadIdx.x;
    if (i < E) {
        int p = atomicAdd(&cursor[dst[i]], 1);
        ssrc[p] = src[i];
        sea[p] = ea[i];
    }
}

// ---------------- Layer 0: aggregate (dim 8), thread per node ----------------
__global__ void agg_l0(const float* __restrict__ x, const int* __restrict__ ssrc,
                       const float4* __restrict__ sea, const int* __restrict__ offs,
                       const float* __restrict__ We0, const float* __restrict__ be0,
                       float* __restrict__ out) {
    __shared__ float Ws[32];
    __shared__ float bs[8];
    int tid = threadIdx.x;
    if (tid < 32) Ws[tid] = We0[tid];
    if (tid < 8) bs[tid] = be0[tid];
    __syncthreads();
    int n = blockIdx.x * 256 + tid;
    float a[8] = {0.f, 0.f, 0.f, 0.f, 0.f, 0.f, 0.f, 0.f};
    int pb = offs[n], pe = offs[n + 1];
    for (int p = pb; p < pe; ++p) {
        int s = ssrc[p];
        float4 ev = sea[p];
        float4 xa = *(const float4*)(x + (size_t)s * 8);
        float4 xb = *(const float4*)(x + (size_t)s * 8 + 4);
        float xs[8] = {xa.x, xa.y, xa.z, xa.w, xb.x, xb.y, xb.z, xb.w};
#pragma unroll
        for (int j2 = 0; j2 < 8; ++j2) {
            float m = xs[j2] + bs[j2] + ev.x * Ws[j2] + ev.y * Ws[8 + j2] +
                      ev.z * Ws[16 + j2] + ev.w * Ws[24 + j2];
            a[j2] += fmaxf(m, 0.f);
        }
    }
    float4 o0 = {a[0], a[1], a[2], a[3]};
    float4 o1 = {a[4], a[5], a[6], a[7]};
    *(float4*)(out + (size_t)n * 8) = o0;
    *(float4*)(out + (size_t)n * 8 + 4) = o1;
}

// ---------------- Layer 0: update h1 = relu((x+agg0)@W0 + b0) ----------------
__global__ void update_l0(const float* __restrict__ x, const float* __restrict__ agg0,
                          const float* __restrict__ W0, const float* __restrict__ b0,
                          float* __restrict__ h1) {
    __shared__ float Ws[8 * 128];
    __shared__ float bs[128];
    __shared__ float ts[2][8];
    int tid = threadIdx.x;
#pragma unroll
    for (int i = tid; i < 1024; i += 256) Ws[i] = W0[i];
    if (tid < 128) bs[tid] = b0[tid];
    int sub = tid >> 7;
    int c = tid & 127;
    int node = blockIdx.x * 2 + sub;
    if (c < 8) ts[sub][c] = x[(size_t)node * 8 + c] + agg0[(size_t)node * 8 + c];
    __syncthreads();
    float acc = bs[c];
#pragma unroll
    for (int k = 0; k < 8; ++k) acc = fmaf(ts[sub][k], Ws[k * 128 + c], acc);
    h1[(size_t)node * 128 + c] = fmaxf(acc, 0.f);
}

// ---------------- Layers 1,2: fused msg+aggregate, wave per node ----------------
// lane owns dims (2*lane, 2*lane+1): one 512B dwordx2 gather per edge, 4-wide unroll
#define MSG(hv, ev)                                                                 \
    {                                                                               \
        float mx = hv.x + bv.x + ev.x * w0.x + ev.y * w1.x + ev.z * w2.x + ev.w * w3.x; \
        float my = hv.y + bv.y + ev.x * w0.y + ev.y * w1.y + ev.z * w2.y + ev.w * w3.y; \
        acc.x += fmaxf(mx, 0.f);                                                    \
        acc.y += fmaxf(my, 0.f);                                                    \
    }

__global__ __launch_bounds__(256) void agg_l(const float2* __restrict__ h2,
                                             const int* __restrict__ ssrc,
                                             const float4* __restrict__ sea,
                                             const int* __restrict__ offs,
                                             const float* __restrict__ We,
                                             const float* __restrict__ be,
                                             float2* __restrict__ out) {
    int tid = threadIdx.x;
    int node = blockIdx.x * 4 + (tid >> 6);
    node = __builtin_amdgcn_readfirstlane(node);
    int lane = tid & 63;
    const float2* We2 = (const float2*)We;
    float2 w0 = We2[lane], w1 = We2[64 + lane], w2 = We2[128 + lane], w3 = We2[192 + lane];
    float2 bv = ((const float2*)be)[lane];
    float2 acc; acc.x = 0.f; acc.y = 0.f;
    int pb = offs[node], pe = offs[node + 1];
    int p = pb;
    for (; p + 4 <= pe; p += 4) {
        int s0 = ssrc[p], s1 = ssrc[p + 1], s2 = ssrc[p + 2], s3 = ssrc[p + 3];
        float4 e0 = sea[p], e1 = sea[p + 1], e2 = sea[p + 2], e3 = sea[p + 3];
        float2 ha = h2[(size_t)s0 * 64 + lane];
        float2 hb = h2[(size_t)s1 * 64 + lane];
        float2 hc = h2[(size_t)s2 * 64 + lane];
        float2 hd = h2[(size_t)s3 * 64 + lane];
        MSG(ha, e0) MSG(hb, e1) MSG(hc, e2) MSG(hd, e3)
    }
    for (; p < pe; ++p) {
        int s0 = ssrc[p];
        float4 e0 = sea[p];
        float2 ha = h2[(size_t)s0 * 64 + lane];
        MSG(ha, e0)
    }
    out[(size_t)node * 64 + lane] = acc;
}

// ---------------- GEMM: out = relu((P [+ Q]) @ W + bias), [N,128]x[128,128] ----------------
// In-place over P or Q is safe: block b reads/writes only rows 32b..32b+31,
// and all its reads complete (staged to LDS) before its writes.
#define ACCROW(m, a)                                                                         \
    acc[m][0] = fmaf(a.x, w0.x, fmaf(a.y, w1.x, fmaf(a.z, w2.x, fmaf(a.w, w3.x, acc[m][0])))); \
    acc[m][1] = fmaf(a.x, w0.y, fmaf(a.y, w1.y, fmaf(a.z, w2.y, fmaf(a.w, w3.y, acc[m][1])))); \
    acc[m][2] = fmaf(a.x, w0.z, fmaf(a.y, w1.z, fmaf(a.z, w2.z, fmaf(a.w, w3.z, acc[m][2])))); \
    acc[m][3] = fmaf(a.x, w0.w, fmaf(a.y, w1.w, fmaf(a.z, w2.w, fmaf(a.w, w3.w, acc[m][3]))));

__global__ __launch_bounds__(256) void gemm_k(const float* __restrict__ P, const float* Q,
                                              const float* __restrict__ W,
                                              const float* __restrict__ bias,
                                              float* out) {
    __shared__ float Ws[64 * 128];  // one 64-row half of W (32 KB)
    __shared__ float As[32 * 128];  // A tile (16 KB)
    int tid = threadIdx.x;
    int r0 = blockIdx.x * 32;
#pragma unroll
    for (int i = 0; i < 4; ++i) {
        int f = tid + 256 * i;
        int r = f >> 5;
        int k4 = f & 31;
        size_t g = (size_t)(r0 + r) * 128 + 4 * k4;
        float4 pv = *(const float4*)(P + g);
        if (Q) {
            float4 qv = *(const float4*)(Q + g);
            pv.x += qv.x; pv.y += qv.y; pv.z += qv.z; pv.w += qv.w;
        }
        *(float4*)(As + (size_t)r * 128 + 4 * k4) = pv;
    }
    int cx = tid & 31;
    int ry = tid >> 5;
    float acc[4][4] = {};
    for (int half = 0; half < 2; ++half) {
        __syncthreads();
        const float4* Wg = (const float4*)(W + (size_t)half * 64 * 128);
#pragma unroll
        for (int i = 0; i < 8; ++i) ((float4*)Ws)[tid + 256 * i] = Wg[tid + 256 * i];
        __syncthreads();
        int kbase = 64 * half;
#pragma unroll 4
        for (int kk = 0; kk < 16; ++kk) {
            int k0 = 4 * kk;
            int ka = kbase + k0;
            float4 w0 = *(const float4*)(Ws + (size_t)(k0 + 0) * 128 + 4 * cx);
            float4 w1 = *(const float4*)(Ws + (size_t)(k0 + 1) * 128 + 4 * cx);
            float4 w2 = *(const float4*)(Ws + (size_t)(k0 + 2) * 128 + 4 * cx);
            float4 w3 = *(const float4*)(Ws + (size_t)(k0 + 3) * 128 + 4 * cx);
            float4 a0 = *(const float4*)(As + (size_t)(4 * ry + 0) * 128 + ka);
            float4 a1 = *(const float4*)(As + (size_t)(4 * ry + 1) * 128 + ka);
            float4 a2 = *(const float4*)(As + (size_t)(4 * ry + 2) * 128 + ka);
            float4 a3 = *(const float4*)(As + (size_t)(4 * ry + 3) * 128 + ka);
            ACCROW(0, a0)
            ACCROW(1, a1)
            ACCROW(2, a2)
            ACCROW(3, a3)
        }
    }
    float4 bv = *(const float4*)(bias + 4 * cx);
    float bb[4] = {bv.x, bv.y, bv.z, bv.w};
#pragma unroll
    for (int m = 0; m < 4; ++m) {
        float4 o;
        o.x = fmaxf(acc[m][0] + bb[0], 0.f);
        o.y = fmaxf(acc[m][1] + bb[1], 0.f);
        o.z = fmaxf(acc[m][2] + bb[2], 0.f);
        o.w = fmaxf(acc[m][3] + bb[3], 0.f);
        *(float4*)(out + (size_t)(r0 + 4 * ry + m) * 128 + 4 * cx) = o;
    }
}

// ---------------- fused actor: L = relu(emb@laW1+lab1)@laW2 + lab2 ----------------
__global__ __launch_bounds__(256) void gemm_logit(const float* __restrict__ P,
                                                  const float* __restrict__ W,
                                                  const float* __restrict__ bias,
                                                  const float* __restrict__ w2,
                                                  const float* __restrict__ b2,
                                                  float* __restrict__ L) {
    __shared__ float Ws[64 * 128];
    __shared__ float As[32 * 128];
    __shared__ float red[32][33];
    int tid = threadIdx.x;
    int r0 = blockIdx.x * 32;
#pragma unroll
    for (int i = 0; i < 4; ++i) {
        int f = tid + 256 * i;
        int r = f >> 5;
        int k4 = f & 31;
        size_t g = (size_t)(r0 + r) * 128 + 4 * k4;
        *(float4*)(As + (size_t)r * 128 + 4 * k4) = *(const float4*)(P + g);
    }
    int cx = tid & 31;
    int ry = tid >> 5;
    float acc[4][4] = {};
    for (int half = 0; half < 2; ++half) {
        __syncthreads();
        const float4* Wg = (const float4*)(W + (size_t)half * 64 * 128);
#pragma unroll
        for (int i = 0; i < 8; ++i) ((float4*)Ws)[tid + 256 * i] = Wg[tid + 256 * i];
        __syncthreads();
        int kbase = 64 * half;
#pragma unroll 4
        for (int kk = 0; kk < 16; ++kk) {
            int k0 = 4 * kk;
            int ka = kbase + k0;
            float4 w0 = *(const float4*)(Ws + (size_t)(k0 + 0) * 128 + 4 * cx);
            float4 w1 = *(const float4*)(Ws + (size_t)(k0 + 1) * 128 + 4 * cx);
            float4 w2r = *(const float4*)(Ws + (size_t)(k0 + 2) * 128 + 4 * cx);
            float4 w3 = *(const float4*)(Ws + (size_t)(k0 + 3) * 128 + 4 * cx);
            float4 a0 = *(const float4*)(As + (size_t)(4 * ry + 0) * 128 + ka);
            float4 a1 = *(const float4*)(As + (size_t)(4 * ry + 1) * 128 + ka);
            float4 a2 = *(const float4*)(As + (size_t)(4 * ry + 2) * 128 + ka);
            float4 a3 = *(const float4*)(As + (size_t)(4 * ry + 3) * 128 + ka);
            {
                float4 w2_ = w2r;
                acc[0][0] = fmaf(a0.x, w0.x, fmaf(a0.y, w1.x, fmaf(a0.z, w2_.x, fmaf(a0.w, w3.x, acc[0][0]))));
                acc[0][1] = fmaf(a0.x, w0.y, fmaf(a0.y, w1.y, fmaf(a0.z, w2_.y, fmaf(a0.w, w3.y, acc[0][1]))));
                acc[0][2] = fmaf(a0.x, w0.z, fmaf(a0.y, w1.z, fmaf(a0.z, w2_.z, fmaf(a0.w, w3.z, acc[0][2]))));
                acc[0][3] = fmaf(a0.x, w0.w, fmaf(a0.y, w1.w, fmaf(a0.z, w2_.w, fmaf(a0.w, w3.w, acc[0][3]))));
                acc[1][0] = fmaf(a1.x, w0.x, fmaf(a1.y, w1.x, fmaf(a1.z, w2_.x, fmaf(a1.w, w3.x, acc[1][0]))));
                acc[1][1] = fmaf(a1.x, w0.y, fmaf(a1.y, w1.y, fmaf(a1.z, w2_.y, fmaf(a1.w, w3.y, acc[1][1]))));
                acc[1][2] = fmaf(a1.x, w0.z, fmaf(a1.y, w1.z, fmaf(a1.z, w2_.z, fmaf(a1.w, w3.z, acc[1][2]))));
                acc[1][3] = fmaf(a1.x, w0.w, fmaf(a1.y, w1.w, fmaf(a1.z, w2_.w, fmaf(a1.w, w3.w, acc[1][3]))));
                acc[2][0] = fmaf(a2.x, w0.x, fmaf(a2.y, w1.x, fmaf(a2.z, w2_.x, fmaf(a2.w, w3.x, acc[2][0]))));
                acc[2][1] = fmaf(a2.x, w0.y, fmaf(a2.y, w1.y, fmaf(a2.z, w2_.y, fmaf(a2.w, w3.y, acc[2][1]))));
                acc[2][2] = fmaf(a2.x, w0.z, fmaf(a2.y, w1.z, fmaf(a2.z, w2_.z, fmaf(a2.w, w3.z, acc[2][2]))));
                acc[2][3] = fmaf(a2.x, w0.w, fmaf(a2.y, w1.w, fmaf(a2.z, w2_.w, fmaf(a2.w, w3.w, acc[2][3]))));
                acc[3][0] = fmaf(a3.x, w0.x, fmaf(a3.y, w1.x, fmaf(a3.z, w2_.x, fmaf(a3.w, w3.x, acc[3][0]))));
                acc[3][1] = fmaf(a3.x, w0.y, fmaf(a3.y, w1.y, fmaf(a3.z, w2_.y, fmaf(a3.w, w3.y, acc[3][1]))));
                acc[3][2] = fmaf(a3.x, w0.z, fmaf(a3.y, w1.z, fmaf(a3.z, w2_.z, fmaf(a3.w, w3.z, acc[3][2]))));
                acc[3][3] = fmaf(a3.x, w0.w, fmaf(a3.y, w1.w, fmaf(a3.z, w2_.w, fmaf(a3.w, w3.w, acc[3][3]))));
            }
        }
    }
    float4 bvv = *(const float4*)(bias + 4 * cx);
    float4 w2v = *(const float4*)(w2 + 4 * cx);
#pragma unroll
    for (int m = 0; m < 4; ++m) {
        float t0 = fmaxf(acc[m][0] + bvv.x, 0.f) * w2v.x;
        float t1 = fmaxf(acc[m][1] + bvv.y, 0.f) * w2v.y;
        float t2 = fmaxf(acc[m][2] + bvv.z, 0.f) * w2v.z;
        float t3 = fmaxf(acc[m][3] + bvv.w, 0.f) * w2v.w;
        red[4 * ry + m][cx] = (t0 + t1) + (t2 + t3);
    }
    __syncthreads();
    if (tid < 32) {
        float s = 0.f;
#pragma unroll
        for (int j = 0; j < 32; ++j) s += red[tid][j];
        L[r0 + tid] = s + b2[0];
    }
}

// ---------------- per-graph softmax + Gumbel-max sampling ----------------
__global__ void sample_k(const float* __restrict__ L, float* __restrict__ ob,
                         int* __restrict__ locInt) {
    int g = blockIdx.x, tid = threadIdx.x;  // 256 threads, 512 nodes
    __shared__ float sh[512];
    __shared__ float rb[256];
    __shared__ int ib[256];
    float l0 = L[g * 512 + tid];
    float l1 = L[g * 512 + 256 + tid];
    rb[tid] = fmaxf(l0, l1);
    __syncthreads();
    for (int s2 = 128; s2 > 0; s2 >>= 1) {
        if (tid < s2) rb[tid] = fmaxf(rb[tid], rb[tid + s2]);
        __syncthreads();
    }
    float mx = rb[0];
    __syncthreads();
    float s0 = l0 - mx, s1 = l1 - mx;
    sh[tid] = s0; sh[256 + tid] = s1;
    float e0 = expf(s0), e1 = expf(s1);
    rb[tid] = e0 + e1;
    __syncthreads();
    for (int s2 = 128; s2 > 0; s2 >>= 1) {
        if (tid < s2) rb[tid] += rb[tid + s2];
        __syncthreads();
    }
    float denom = rb[0];
    __syncthreads();
    rb[tid] = e0 * s0 + e1 * s1;
    __syncthreads();
    for (int s2 = 128; s2 > 0; s2 >>= 1) {
        if (tid < s2) rb[tid] += rb[tid + s2];
        __syncthreads();
    }
    float sum2 = rb[0];
    __syncthreads();
    unsigned i0 = (unsigned)(g * 512 + tid);
    unsigned i1 = i0 + 256u;
    float p0 = l0 - logf(-logf(unif_loc(i0)));
    float p1 = l1 - logf(-logf(unif_loc(i1)));
    rb[tid] = fmaxf(p0, p1);
    __syncthreads();
    for (int s2 = 128; s2 > 0; s2 >>= 1) {
        if (tid < s2) rb[tid] = fmaxf(rb[tid], rb[tid + s2]);
        __syncthreads();
    }
    float pmax = rb[0];
    __syncthreads();
    int c0 = (p0 >= pmax) ? tid : 0x7FFFFFFF;
    int c1 = (p1 >= pmax) ? (tid + 256) : 0x7FFFFFFF;
    ib[tid] = min(c0, c1);
    __syncthreads();
    for (int s2 = 128; s2 > 0; s2 >>= 1) {
        if (tid < s2) ib[tid] = min(ib[tid], ib[tid + s2]);
        __syncthreads();
    }
    if (tid == 0) {
        int li = ib[0];
        float logD = logf(denom);
        ob[g] = (float)(g * 512 + li);          // locations
        ob[1024 + g] = sh[li] - logD;           // loc_log_probs
        ob[2048 + g] = logD - sum2 / denom;     // loc_entropy
        locInt[g] = g * 512 + li;
    }
}

// ---------------- pooled = segment_sum(emb) ----------------
__global__ void pool_k(const float* __restrict__ emb, float* __restrict__ pooled) {
    int g = blockIdx.x, tid = threadIdx.x;  // 512 threads
    int c = tid & 127, rg = tid >> 7;
    __shared__ float sh[512];
    float s0 = 0.f, s1 = 0.f, s2 = 0.f, s3 = 0.f;
    const float* base = emb + ((size_t)g * 512 + (size_t)rg * 128) * 128 + c;
    for (int n = 0; n < 128; n += 4) {
        s0 += base[(size_t)(n + 0) * 128];
        s1 += base[(size_t)(n + 1) * 128];
        s2 += base[(size_t)(n + 2) * 128];
        s3 += base[(size_t)(n + 3) * 128];
    }
    sh[tid] = (s0 + s1) + (s2 + s3);
    __syncthreads();
    if (rg == 0) pooled[g * 128 + c] = sh[c] + sh[128 + c] + sh[256 + c] + sh[384 + c];
}

// ---------------- heads: mutation actor + both critics ----------------
__global__ void heads_k(const float* __restrict__ emb, const float* __restrict__ pooled,
                        const int* __restrict__ locInt,
                        const float* __restrict__ maW1, const float* __restrict__ mab1,
                        const float* __restrict__ maW2, const float* __restrict__ mab2,
                        const float* __restrict__ lcW1, const float* __restrict__ lcb1,
                        const float* __restrict__ lcW2, const float* __restrict__ lcb2,
                        const float* __restrict__ mcW1, const float* __restrict__ mcb1,
                        const float* __restrict__ mcW2, const float* __restrict__ mcb2,
                        float* __restrict__ ob) {
    int g = blockIdx.x, tid = threadIdx.x;  // 128 threads
    __shared__ float sel[128], pl[128];
    __shared__ float red[4][128];
    __shared__ float red1[128];
    __shared__ float mcv_sh;
    sel[tid] = emb[(size_t)locInt[g] * 128 + tid];
    pl[tid] = pooled[g * 128 + tid];
    __syncthreads();
    float h = mab1[tid];
    for (int k = 0; k < 128; ++k) h = fmaf(sel[k], maW1[k * 128 + tid], h);
    h = fmaxf(h, 0.f);
    red[0][tid] = h * maW2[tid * 4 + 0];
    red[1][tid] = h * maW2[tid * 4 + 1];
    red[2][tid] = h * maW2[tid * 4 + 2];
    red[3][tid] = h * maW2[tid * 4 + 3];
    __syncthreads();
    for (int s2 = 64; s2 > 0; s2 >>= 1) {
        if (tid < s2) {
            red[0][tid] += red[0][tid + s2];
            red[1][tid] += red[1][tid + s2];
            red[2][tid] += red[2][tid + s2];
            red[3][tid] += red[3][tid + s2];
        }
        __syncthreads();
    }
    float h2 = mcb1[tid];
    for (int k = 0; k < 128; ++k) h2 = fmaf(sel[k], mcW1[k * 128 + tid], h2);
    h2 = fmaxf(h2, 0.f);
    red1[tid] = h2 * mcW2[tid];
    __syncthreads();
    for (int s2 = 64; s2 > 0; s2 >>= 1) {
        if (tid < s2) red1[tid] += red1[tid + s2];
        __syncthreads();
    }
    if (tid == 0) mcv_sh = red1[0] + mcb2[0];
    __syncthreads();
    float h3 = lcb1[tid];
    for (int k = 0; k < 128; ++k) h3 = fmaf(pl[k], lcW1[k * 128 + tid], h3);
    h3 = fmaxf(h3, 0.f);
    red1[tid] = h3 * lcW2[tid];
    __syncthreads();
    for (int s2 = 64; s2 > 0; s2 >>= 1) {
        if (tid < s2) red1[tid] += red1[tid + s2];
        __syncthreads();
    }
    if (tid == 0) {
        float lcv = red1[0] + lcb2[0];
        float lg[4];
#pragma unroll
        for (int c = 0; c < 4; ++c) lg[c] = red[c][0] + mab2[c];
        unsigned fk0, fk1;
        tf2x32(0u, 42u, 0u, 1u, fk0, fk1);
        float gmb[4];
#pragma unroll
        for (int c = 0; c < 4; ++c) {
            unsigned m = (unsigned)(g * 4 + c);
            unsigned j = m & 1023u;
            unsigned halfb = m >> 10;
            unsigned o0, o1;
            tf2x32(fk0, fk1, j, j + 1024u, o0, o1);
            unsigned bits = halfb ? o1 : o0;
            float f = __uint_as_float((bits >> 9) | 0x3F800000u) - 1.0f;
            const float tiny = 1.17549435e-38f;
            float u = fmaxf(tiny, __fadd_rn(__fmul_rn(f, 1.0f), tiny));
            gmb[c] = -logf(-logf(u));
        }
        int best = 0;
        float bz = gmb[0] + lg[0];
#pragma unroll
        for (int c = 1; c < 4; ++c) {
            float z = gmb[c] + lg[c];
            if (z > bz) { bz = z; best = c; }
        }
        float M = fmaxf(fmaxf(lg[0], lg[1]), fmaxf(lg[2], lg[3]));
        float se = 0.f;
#pragma unroll
        for (int c = 0; c < 4; ++c) se += expf(lg[c] - M);
        float lse = M + logf(se);
        float ent = 0.f;
#pragma unroll
        for (int c = 0; c < 4; ++c) {
            float lp = lg[c] - lse;
            ent -= expf(lp) * lp;
        }
        ob[512 + g] = (float)best;        // mutations
        ob[1536 + g] = lg[best] - lse;    // mut_log_probs
        ob[2560 + g] = ent;               // mut_entropy
        ob[3072 + g] = lcv;               // loc_values
        ob[3584 + g] = mcv_sh;            // mut_values
    }
}

// ---------------- launch ----------------
extern "C" void kernel_launch(void* const* d_in, const int* in_sizes, int n_in,
                              void* d_out, int out_size, void* d_ws, size_t ws_size,
                              hipStream_t stream) {
    const float* x   = (const float*)d_in[0];
    const int* ei    = (const int*)d_in[1];
    const float* ea  = (const float*)d_in[2];
    const float* We0 = (const float*)d_in[5];
    const float* be0 = (const float*)d_in[6];
    const float* W0  = (const float*)d_in[7];
    const float* b0  = (const float*)d_in[8];
    const float* We1 = (const float*)d_in[9];
    const float* be1 = (const float*)d_in[10];
    const float* W1  = (const float*)d_in[11];
    const float* b1  = (const float*)d_in[12];
    const float* We2 = (const float*)d_in[13];
    const float* be2 = (const float*)d_in[14];
    const float* W2  = (const float*)d_in[15];
    const float* b2  = (const float*)d_in[16];
    const float* laW1 = (const float*)d_in[17];
    const float* lab1 = (const float*)d_in[18];
    const float* laW2 = (const float*)d_in[19];
    const float* lab2 = (const float*)d_in[20];
    const float* maW1 = (const float*)d_in[21];
    const float* mab1 = (const float*)d_in[22];
    const float* maW2 = (const float*)d_in[23];
    const float* mab2 = (const float*)d_in[24];
    const float* lcW1 = (const float*)d_in[25];
    const float* lcb1 = (const float*)d_in[26];
    const float* lcW2 = (const float*)d_in[27];
    const float* lcb2 = (const float*)d_in[28];
    const float* mcW1 = (const float*)d_in[29];
    const float* mcb1 = (const float*)d_in[30];
    const float* mcW2 = (const float*)d_in[31];
    const float* mcb2 = (const float*)d_in[32];

    float* out = (float*)d_out;
    char* ws = (char*)d_ws;
    size_t off = 0;
    auto alloc = [&](size_t bytes) -> void* {
        void* p = ws + off;
        off += (bytes + 255) & ~(size_t)255;
        return p;
    };
    float* U    = (float*)alloc((size_t)NN * 128 * 4);  // 128 MB ping-pong
    int* counts = (int*)alloc((size_t)NN * 4);
    int* offs   = (int*)alloc((size_t)(NN + 1) * 4);
    int* cursor = (int*)alloc((size_t)NN * 4);
    int* ssrc   = (int*)alloc((size_t)EE * 4);          // 4 MB: src in dst-sorted order
    float4* sea = (float4*)alloc((size_t)EE * 16);      // 16 MB: edge_attr sorted
    int* bsum   = (int*)alloc(512 * 4);
    int* bbase  = (int*)alloc(512 * 4);
    int* bscr   = (int*)alloc(512 * 4);
    float* Lg   = (float*)alloc((size_t)NN * 4);        // 1 MB
    float* pooled = (float*)alloc((size_t)BB * 128 * 4);
    int* locInt = (int*)alloc((size_t)BB * 4);
    // total ws ≈ 153 MB

    const int* src = ei;
    const int* dstA = ei + EE;
    float* V = out + 4096;        // emb region of d_out, used as ping-pong buffer
    float* agg0 = U;              // aliases U; consumed before U is reused

    // CSR by destination (fixed across layers), edges scattered into sorted order
    hipMemsetAsync(counts, 0, (size_t)NN * 4, stream);
    csr_count<<<EE / 256, 256, 0, stream>>>(dstA, counts, EE);
    scan512<<<NN / 512, 512, 0, stream>>>(counts, offs, bsum);
    scan512<<<1, 512, 0, stream>>>(bsum, bbase, bscr);
    scan_fix<<<NN / 512, 512, 0, stream>>>(offs, bbase, cursor, NN, EE);
    csr_fill<<<EE / 256, 256, 0, stream>>>(dstA, src, (const float4*)ea, cursor, ssrc, sea, EE);

    // GNN layers (ping-pong: V=d_out emb region, U=ws)
    agg_l0<<<NN / 256, 256, 0, stream>>>(x, ssrc, sea, offs, We0, be0, agg0);
    update_l0<<<NN / 2, 256, 0, stream>>>(x, agg0, W0, b0, V);              // h1 -> V
    agg_l<<<NN / 4, 256, 0, stream>>>((const float2*)V, ssrc, sea, offs, We1, be1, (float2*)U);
    gemm_k<<<NN / 32, 256, 0, stream>>>(V, U, W1, b1, U);                   // h2 -> U
    agg_l<<<NN / 4, 256, 0, stream>>>((const float2*)U, ssrc, sea, offs, We2, be2, (float2*)V);
    gemm_k<<<NN / 32, 256, 0, stream>>>(U, V, W2, b2, V);                   // emb -> V (d_out)

    // location actor (fused GEMM + logit)
    gemm_logit<<<NN / 32, 256, 0, stream>>>(V, laW1, lab1, laW2, lab2, Lg);
    sample_k<<<BB, 256, 0, stream>>>(Lg, out, locInt);

    // pooling + heads
    pool_k<<<BB, 512, 0, stream>>>(V, pooled);
    heads_k<<<BB, 128, 0, stream>>>(V, pooled, locInt, maW1, mab1, maW2, mab2,
                                    lcW1, lcb1, lcW2, lcb2, mcW1, mcb1, mcW2, mcb2, out);
}

// Round 5
// 1016.618 us; speedup vs baseline: 1.3482x; 1.1069x over previous
//
#include <hip/hip_runtime.h>
#include <cstdint>
#include <cstddef>

#define NN 262144
#define EE 1048576
#define BB 512
#define SEG 512

// ---------------- Threefry-2x32 (exact JAX replica) ----------------
__device__ __forceinline__ unsigned rotl32(unsigned x, int r) {
    return (x << r) | (x >> (32 - r));
}

__device__ __forceinline__ void tf2x32(unsigned k0, unsigned k1, unsigned x0, unsigned x1,
                                       unsigned& o0, unsigned& o1) {
    unsigned ks[3] = {k0, k1, k0 ^ k1 ^ 0x1BD11BDAu};
    x0 += ks[0]; x1 += ks[1];
    const int R0[4] = {13, 15, 26, 6};
    const int R1[4] = {17, 29, 16, 24};
#pragma unroll
    for (int i = 0; i < 5; ++i) {
        const int* R = (i & 1) ? R1 : R0;
#pragma unroll
        for (int j = 0; j < 4; ++j) {
            x0 += x1;
            x1 = rotl32(x1, R[j]);
            x1 ^= x0;
        }
        x0 += ks[(i + 1) % 3];
        x1 += ks[(i + 2) % 3] + (unsigned)(i + 1);
    }
    o0 = x0; o1 = x1;
}

__device__ __forceinline__ float unif_loc(unsigned idx) {
    unsigned j = idx & (NN / 2 - 1);
    unsigned half = idx >> 17;
    unsigned o0, o1;
    tf2x32(0u, 42u, j, j + (unsigned)(NN / 2), o0, o1);
    unsigned bits = half ? o1 : o0;
    float f = __uint_as_float((bits >> 9) | 0x3F800000u) - 1.0f;
    const float minv = 1e-6f;
    const float maxv = 1.0f - 1e-6f;
    const float span = maxv - minv;
    return fmaxf(minv, __fadd_rn(__fmul_rn(f, span), minv));
}

// ---------------- CSR build ----------------
__global__ void csr_count(const int* __restrict__ dst, int* __restrict__ counts, int E) {
    int i = blockIdx.x * 256 + threadIdx.x;
    if (i < E) atomicAdd(&counts[dst[i]], 1);
}

__global__ void scan512(const int* __restrict__ in, int* __restrict__ outExcl, int* __restrict__ bsum) {
    __shared__ int s[512];
    int b = blockIdx.x, tid = threadIdx.x;
    int v = in[(size_t)b * 512 + tid];
    s[tid] = v;
    __syncthreads();
    for (int d = 1; d < 512; d <<= 1) {
        int add = (tid >= d) ? s[tid - d] : 0;
        __syncthreads();
        s[tid] += add;
        __syncthreads();
    }
    outExcl[(size_t)b * 512 + tid] = s[tid] - v;
    if (tid == 511) bsum[b] = s[511];
}

__global__ void scan_fix(int* __restrict__ offs, const int* __restrict__ bbase,
                         int* __restrict__ cursor, int N, int E) {
    int gid = blockIdx.x * 512 + threadIdx.x;
    int v = offs[gid] + bbase[blockIdx.x];
    offs[gid] = v;
    cursor[gid] = v;
    if (gid == 0) offs[N] = E;
}

__global__ void csr_fill(const int* __restrict__ dst, const int* __restrict__ src,
                         const float4* __restrict__ ea, int* __restrict__ cursor,
                         int* __restrict__ ssrc, float4* __restrict__ sea, int E) {
    int i = blockIdx.x * 256 + threadIdx.x;
    if (i < E) {
        int p = atomicAdd(&cursor[dst[i]], 1);
        ssrc[p] = src[i];
        sea[p] = ea[i];
    }
}

// ---------------- Layer 0: aggregate (dim 8) ----------------
__global__ void agg_l0(const float* __restrict__ x, const int* __restrict__ ssrc,
                       const float4* __restrict__ sea, const int* __restrict__ offs,
                       const float* __restrict__ We0, const float* __restrict__ be0,
                       float* __restrict__ out) {
    __shared__ float Ws[32];
    __shared__ float bs[8];
    int tid = threadIdx.x;
    if (tid < 32) Ws[tid] = We0[tid];
    if (tid < 8) bs[tid] = be0[tid];
    __syncthreads();
    int n = blockIdx.x * 256 + tid;
    float a[8] = {0.f, 0.f, 0.f, 0.f, 0.f, 0.f, 0.f, 0.f};
    int pb = offs[n], pe = offs[n + 1];
    for (int p = pb; p < pe; ++p) {
        int s = ssrc[p];
        float4 ev = sea[p];
        float4 xa = *(const float4*)(x + (size_t)s * 8);
        float4 xb = *(const float4*)(x + (size_t)s * 8 + 4);
        float xs[8] = {xa.x, xa.y, xa.z, xa.w, xb.x, xb.y, xb.z, xb.w};
#pragma unroll
        for (int j2 = 0; j2 < 8; ++j2) {
            float m = xs[j2] + bs[j2] + ev.x * Ws[j2] + ev.y * Ws[8 + j2] +
                      ev.z * Ws[16 + j2] + ev.w * Ws[24 + j2];
            a[j2] += fmaxf(m, 0.f);
        }
    }
    float4 o0 = {a[0], a[1], a[2], a[3]};
    float4 o1 = {a[4], a[5], a[6], a[7]};
    *(float4*)(out + (size_t)n * 8) = o0;
    *(float4*)(out + (size_t)n * 8 + 4) = o1;
}

// ---------------- Layer 0 update ----------------
__global__ void update_l0(const float* __restrict__ x, const float* __restrict__ agg0,
                          const float* __restrict__ W0, const float* __restrict__ b0,
                          float* __restrict__ h1) {
    __shared__ float Ws[8 * 128];
    __shared__ float bs[128];
    __shared__ float ts[2][8];
    int tid = threadIdx.x;
#pragma unroll
    for (int i = tid; i < 1024; i += 256) Ws[i] = W0[i];
    if (tid < 128) bs[tid] = b0[tid];
    int sub = tid >> 7;
    int c = tid & 127;
    int node = blockIdx.x * 2 + sub;
    if (c < 8) ts[sub][c] = x[(size_t)node * 8 + c] + agg0[(size_t)node * 8 + c];
    __syncthreads();
    float acc = bs[c];
#pragma unroll
    for (int k = 0; k < 8; ++k) acc = fmaf(ts[sub][k], Ws[k * 128 + c], acc);
    h1[(size_t)node * 128 + c] = fmaxf(acc, 0.f);
}

// ---------------- Layers 1,2: fused msg+aggregate, wave per node ----------------
#define MSG(hv, ev)                                                                 \
    {                                                                               \
        float mx = hv.x + bv.x + ev.x * w0.x + ev.y * w1.x + ev.z * w2.x + ev.w * w3.x; \
        float my = hv.y + bv.y + ev.x * w0.y + ev.y * w1.y + ev.z * w2.y + ev.w * w3.y; \
        acc.x += fmaxf(mx, 0.f);                                                    \
        acc.y += fmaxf(my, 0.f);                                                    \
    }

__global__ __launch_bounds__(256) void agg_l(const float2* __restrict__ h2,
                                             const int* __restrict__ ssrc,
                                             const float4* __restrict__ sea,
                                             const int* __restrict__ offs,
                                             const float* __restrict__ We,
                                             const float* __restrict__ be,
                                             float2* __restrict__ out) {
    int tid = threadIdx.x;
    int node = blockIdx.x * 4 + (tid >> 6);
    node = __builtin_amdgcn_readfirstlane(node);
    int lane = tid & 63;
    const float2* We2 = (const float2*)We;
    float2 w0 = We2[lane], w1 = We2[64 + lane], w2 = We2[128 + lane], w3 = We2[192 + lane];
    float2 bv = ((const float2*)be)[lane];
    float2 acc; acc.x = 0.f; acc.y = 0.f;
    int pb = offs[node], pe = offs[node + 1];
    int p = pb;
    for (; p + 4 <= pe; p += 4) {
        int s0 = ssrc[p], s1 = ssrc[p + 1], s2 = ssrc[p + 2], s3 = ssrc[p + 3];
        float4 e0 = sea[p], e1 = sea[p + 1], e2 = sea[p + 2], e3 = sea[p + 3];
        float2 ha = h2[(size_t)s0 * 64 + lane];
        float2 hb = h2[(size_t)s1 * 64 + lane];
        float2 hc = h2[(size_t)s2 * 64 + lane];
        float2 hd = h2[(size_t)s3 * 64 + lane];
        MSG(ha, e0) MSG(hb, e1) MSG(hc, e2) MSG(hd, e3)
    }
    for (; p < pe; ++p) {
        int s0 = ssrc[p];
        float4 e0 = sea[p];
        float2 ha = h2[(size_t)s0 * 64 + lane];
        MSG(ha, e0)
    }
    out[(size_t)node * 64 + lane] = acc;
}

// ====== 128x128-tile GEMM, 8x8 per thread, BK=32, LDS-inst-minimized ======
// As transposed [k][m] stride 132 (breaks write-bank aliasing; reads are
// 4-address broadcasts). Ws slot-swizzled so the 16 read addresses cover all
// bank groups evenly. In-place safe: block reads only rows r0..r0+127, all
// global reads happen before its writes.
__device__ __forceinline__ int wslot(int c) {   // logical float4-chunk -> storage slot
    return (c & 1) ? (16 + (((c >> 1) + 4) & 15)) : (c >> 1);
}

__global__ __launch_bounds__(256, 4) void gemm_k(const float* __restrict__ P, const float* Q,
                                                 const float* __restrict__ W,
                                                 const float* __restrict__ bias,
                                                 float* out) {
    __shared__ float As[32][132];
    __shared__ float Ws[32][128];
    int tid = threadIdx.x;
    int r0 = blockIdx.x * 128;
    int ty = tid >> 4, tx = tid & 15;
    int wo1 = 4 * tx;                    // slot tx
    int wo2 = 64 + 4 * ((tx + 4) & 15);  // slot 16+((tx+4)&15)
    float acc[8][8] = {};
    for (int kc = 0; kc < 4; ++kc) {
        int k0 = kc * 32;
        __syncthreads();
#pragma unroll
        for (int i = 0; i < 4; ++i) {
            int f = tid + 256 * i;
            int r = f >> 3;
            int c4 = f & 7;
            size_t g = (size_t)(r0 + r) * 128 + k0 + 4 * c4;
            float4 pv = *(const float4*)(P + g);
            if (Q) {
                float4 qv = *(const float4*)(Q + g);
                pv.x += qv.x; pv.y += qv.y; pv.z += qv.z; pv.w += qv.w;
            }
            As[4 * c4 + 0][r] = pv.x;
            As[4 * c4 + 1][r] = pv.y;
            As[4 * c4 + 2][r] = pv.z;
            As[4 * c4 + 3][r] = pv.w;
        }
#pragma unroll
        for (int i = 0; i < 4; ++i) {
            int f = tid + 256 * i;
            int k = f >> 5;
            int c4 = f & 31;
            float4 wv = *(const float4*)(W + (size_t)(k0 + k) * 128 + 4 * c4);
            *(float4*)&Ws[k][4 * wslot(c4)] = wv;
        }
        __syncthreads();
#pragma unroll 4
        for (int k = 0; k < 32; ++k) {
            float4 a0 = *(const float4*)&As[k][8 * ty];
            float4 a1 = *(const float4*)&As[k][8 * ty + 4];
            float4 wv0 = *(const float4*)&Ws[k][wo1];
            float4 wv1 = *(const float4*)&Ws[k][wo2];
            float av[8] = {a0.x, a0.y, a0.z, a0.w, a1.x, a1.y, a1.z, a1.w};
            float wv[8] = {wv0.x, wv0.y, wv0.z, wv0.w, wv1.x, wv1.y, wv1.z, wv1.w};
#pragma unroll
            for (int m = 0; m < 8; ++m)
#pragma unroll
                for (int n = 0; n < 8; ++n)
                    acc[m][n] = fmaf(av[m], wv[n], acc[m][n]);
        }
    }
    float4 b0 = *(const float4*)(bias + 8 * tx);
    float4 b1 = *(const float4*)(bias + 8 * tx + 4);
#pragma unroll
    for (int m = 0; m < 8; ++m) {
        float4 o0, o1;
        o0.x = fmaxf(acc[m][0] + b0.x, 0.f);
        o0.y = fmaxf(acc[m][1] + b0.y, 0.f);
        o0.z = fmaxf(acc[m][2] + b0.z, 0.f);
        o0.w = fmaxf(acc[m][3] + b0.w, 0.f);
        o1.x = fmaxf(acc[m][4] + b1.x, 0.f);
        o1.y = fmaxf(acc[m][5] + b1.y, 0.f);
        o1.z = fmaxf(acc[m][6] + b1.z, 0.f);
        o1.w = fmaxf(acc[m][7] + b1.w, 0.f);
        size_t g = (size_t)(r0 + 8 * ty + m) * 128 + 8 * tx;
        *(float4*)(out + g) = o0;
        *(float4*)(out + g + 4) = o1;
    }
}

// ---- fused actor: L = relu(emb@laW1+lab1)@laW2 + lab2, same tile shape ----
__global__ __launch_bounds__(256, 4) void gemm_logit(const float* __restrict__ P,
                                                     const float* __restrict__ W,
                                                     const float* __restrict__ bias,
                                                     const float* __restrict__ w2,
                                                     const float* __restrict__ b2,
                                                     float* __restrict__ L) {
    __shared__ float As[32][132];
    __shared__ float Ws[32][128];
    int tid = threadIdx.x;
    int r0 = blockIdx.x * 128;
    int ty = tid >> 4, tx = tid & 15;
    int wo1 = 4 * tx;
    int wo2 = 64 + 4 * ((tx + 4) & 15);
    float acc[8][8] = {};
    for (int kc = 0; kc < 4; ++kc) {
        int k0 = kc * 32;
        __syncthreads();
#pragma unroll
        for (int i = 0; i < 4; ++i) {
            int f = tid + 256 * i;
            int r = f >> 3;
            int c4 = f & 7;
            size_t g = (size_t)(r0 + r) * 128 + k0 + 4 * c4;
            float4 pv = *(const float4*)(P + g);
            As[4 * c4 + 0][r] = pv.x;
            As[4 * c4 + 1][r] = pv.y;
            As[4 * c4 + 2][r] = pv.z;
            As[4 * c4 + 3][r] = pv.w;
        }
#pragma unroll
        for (int i = 0; i < 4; ++i) {
            int f = tid + 256 * i;
            int k = f >> 5;
            int c4 = f & 31;
            float4 wv = *(const float4*)(W + (size_t)(k0 + k) * 128 + 4 * c4);
            *(float4*)&Ws[k][4 * wslot(c4)] = wv;
        }
        __syncthreads();
#pragma unroll 4
        for (int k = 0; k < 32; ++k) {
            float4 a0 = *(const float4*)&As[k][8 * ty];
            float4 a1 = *(const float4*)&As[k][8 * ty + 4];
            float4 wv0 = *(const float4*)&Ws[k][wo1];
            float4 wv1 = *(const float4*)&Ws[k][wo2];
            float av[8] = {a0.x, a0.y, a0.z, a0.w, a1.x, a1.y, a1.z, a1.w};
            float wv[8] = {wv0.x, wv0.y, wv0.z, wv0.w, wv1.x, wv1.y, wv1.z, wv1.w};
#pragma unroll
            for (int m = 0; m < 8; ++m)
#pragma unroll
                for (int n = 0; n < 8; ++n)
                    acc[m][n] = fmaf(av[m], wv[n], acc[m][n]);
        }
    }
    float4 b0 = *(const float4*)(bias + 8 * tx);
    float4 b1 = *(const float4*)(bias + 8 * tx + 4);
    float4 w2a = *(const float4*)(w2 + 8 * tx);
    float4 w2b = *(const float4*)(w2 + 8 * tx + 4);
    float b2v = b2[0];
#pragma unroll
    for (int m = 0; m < 8; ++m) {
        float v = fmaxf(acc[m][0] + b0.x, 0.f) * w2a.x;
        v += fmaxf(acc[m][1] + b0.y, 0.f) * w2a.y;
        v += fmaxf(acc[m][2] + b0.z, 0.f) * w2a.z;
        v += fmaxf(acc[m][3] + b0.w, 0.f) * w2a.w;
        v += fmaxf(acc[m][4] + b1.x, 0.f) * w2b.x;
        v += fmaxf(acc[m][5] + b1.y, 0.f) * w2b.y;
        v += fmaxf(acc[m][6] + b1.z, 0.f) * w2b.z;
        v += fmaxf(acc[m][7] + b1.w, 0.f) * w2b.w;
        v += __shfl_down(v, 8, 16);
        v += __shfl_down(v, 4, 16);
        v += __shfl_down(v, 2, 16);
        v += __shfl_down(v, 1, 16);
        if (tx == 0) L[r0 + 8 * ty + m] = v + b2v;
    }
}

// ---------------- per-graph softmax + Gumbel-max sampling ----------------
__global__ void sample_k(const float* __restrict__ L, float* __restrict__ ob,
                         int* __restrict__ locInt) {
    int g = blockIdx.x, tid = threadIdx.x;
    __shared__ float sh[512];
    __shared__ float rb[256];
    __shared__ int ib[256];
    float l0 = L[g * 512 + tid];
    float l1 = L[g * 512 + 256 + tid];
    rb[tid] = fmaxf(l0, l1);
    __syncthreads();
    for (int s2 = 128; s2 > 0; s2 >>= 1) {
        if (tid < s2) rb[tid] = fmaxf(rb[tid], rb[tid + s2]);
        __syncthreads();
    }
    float mx = rb[0];
    __syncthreads();
    float s0 = l0 - mx, s1 = l1 - mx;
    sh[tid] = s0; sh[256 + tid] = s1;
    float e0 = expf(s0), e1 = expf(s1);
    rb[tid] = e0 + e1;
    __syncthreads();
    for (int s2 = 128; s2 > 0; s2 >>= 1) {
        if (tid < s2) rb[tid] += rb[tid + s2];
        __syncthreads();
    }
    float denom = rb[0];
    __syncthreads();
    rb[tid] = e0 * s0 + e1 * s1;
    __syncthreads();
    for (int s2 = 128; s2 > 0; s2 >>= 1) {
        if (tid < s2) rb[tid] += rb[tid + s2];
        __syncthreads();
    }
    float sum2 = rb[0];
    __syncthreads();
    unsigned i0 = (unsigned)(g * 512 + tid);
    unsigned i1 = i0 + 256u;
    float p0 = l0 - logf(-logf(unif_loc(i0)));
    float p1 = l1 - logf(-logf(unif_loc(i1)));
    rb[tid] = fmaxf(p0, p1);
    __syncthreads();
    for (int s2 = 128; s2 > 0; s2 >>= 1) {
        if (tid < s2) rb[tid] = fmaxf(rb[tid], rb[tid + s2]);
        __syncthreads();
    }
    float pmax = rb[0];
    __syncthreads();
    int c0 = (p0 >= pmax) ? tid : 0x7FFFFFFF;
    int c1 = (p1 >= pmax) ? (tid + 256) : 0x7FFFFFFF;
    ib[tid] = min(c0, c1);
    __syncthreads();
    for (int s2 = 128; s2 > 0; s2 >>= 1) {
        if (tid < s2) ib[tid] = min(ib[tid], ib[tid + s2]);
        __syncthreads();
    }
    if (tid == 0) {
        int li = ib[0];
        float logD = logf(denom);
        ob[g] = (float)(g * 512 + li);
        ob[1024 + g] = sh[li] - logD;
        ob[2048 + g] = logD - sum2 / denom;
        locInt[g] = g * 512 + li;
    }
}

// ---------------- pooled = segment_sum(emb) ----------------
__global__ void pool_k(const float* __restrict__ emb, float* __restrict__ pooled) {
    int g = blockIdx.x, tid = threadIdx.x;
    int c = tid & 127, rg = tid >> 7;
    __shared__ float sh[512];
    float s0 = 0.f, s1 = 0.f, s2 = 0.f, s3 = 0.f;
    const float* base = emb + ((size_t)g * 512 + (size_t)rg * 128) * 128 + c;
    for (int n = 0; n < 128; n += 4) {
        s0 += base[(size_t)(n + 0) * 128];
        s1 += base[(size_t)(n + 1) * 128];
        s2 += base[(size_t)(n + 2) * 128];
        s3 += base[(size_t)(n + 3) * 128];
    }
    sh[tid] = (s0 + s1) + (s2 + s3);
    __syncthreads();
    if (rg == 0) pooled[g * 128 + c] = sh[c] + sh[128 + c] + sh[256 + c] + sh[384 + c];
}

// ---------------- heads ----------------
__global__ void heads_k(const float* __restrict__ emb, const float* __restrict__ pooled,
                        const int* __restrict__ locInt,
                        const float* __restrict__ maW1, const float* __restrict__ mab1,
                        const float* __restrict__ maW2, const float* __restrict__ mab2,
                        const float* __restrict__ lcW1, const float* __restrict__ lcb1,
                        const float* __restrict__ lcW2, const float* __restrict__ lcb2,
                        const float* __restrict__ mcW1, const float* __restrict__ mcb1,
                        const float* __restrict__ mcW2, const float* __restrict__ mcb2,
                        float* __restrict__ ob) {
    int g = blockIdx.x, tid = threadIdx.x;
    __shared__ float sel[128], pl[128];
    __shared__ float red[4][128];
    __shared__ float red1[128];
    __shared__ float mcv_sh;
    sel[tid] = emb[(size_t)locInt[g] * 128 + tid];
    pl[tid] = pooled[g * 128 + tid];
    __syncthreads();
    float h = mab1[tid];
    for (int k = 0; k < 128; ++k) h = fmaf(sel[k], maW1[k * 128 + tid], h);
    h = fmaxf(h, 0.f);
    red[0][tid] = h * maW2[tid * 4 + 0];
    red[1][tid] = h * maW2[tid * 4 + 1];
    red[2][tid] = h * maW2[tid * 4 + 2];
    red[3][tid] = h * maW2[tid * 4 + 3];
    __syncthreads();
    for (int s2 = 64; s2 > 0; s2 >>= 1) {
        if (tid < s2) {
            red[0][tid] += red[0][tid + s2];
            red[1][tid] += red[1][tid + s2];
            red[2][tid] += red[2][tid + s2];
            red[3][tid] += red[3][tid + s2];
        }
        __syncthreads();
    }
    float h2 = mcb1[tid];
    for (int k = 0; k < 128; ++k) h2 = fmaf(sel[k], mcW1[k * 128 + tid], h2);
    h2 = fmaxf(h2, 0.f);
    red1[tid] = h2 * mcW2[tid];
    __syncthreads();
    for (int s2 = 64; s2 > 0; s2 >>= 1) {
        if (tid < s2) red1[tid] += red1[tid + s2];
        __syncthreads();
    }
    if (tid == 0) mcv_sh = red1[0] + mcb2[0];
    __syncthreads();
    float h3 = lcb1[tid];
    for (int k = 0; k < 128; ++k) h3 = fmaf(pl[k], lcW1[k * 128 + tid], h3);
    h3 = fmaxf(h3, 0.f);
    red1[tid] = h3 * lcW2[tid];
    __syncthreads();
    for (int s2 = 64; s2 > 0; s2 >>= 1) {
        if (tid < s2) red1[tid] += red1[tid + s2];
        __syncthreads();
    }
    if (tid == 0) {
        float lcv = red1[0] + lcb2[0];
        float lg[4];
#pragma unroll
        for (int c = 0; c < 4; ++c) lg[c] = red[c][0] + mab2[c];
        unsigned fk0, fk1;
        tf2x32(0u, 42u, 0u, 1u, fk0, fk1);
        float gmb[4];
#pragma unroll
        for (int c = 0; c < 4; ++c) {
            unsigned m = (unsigned)(g * 4 + c);
            unsigned j = m & 1023u;
            unsigned halfb = m >> 10;
            unsigned o0, o1;
            tf2x32(fk0, fk1, j, j + 1024u, o0, o1);
            unsigned bits = halfb ? o1 : o0;
            float f = __uint_as_float((bits >> 9) | 0x3F800000u) - 1.0f;
            const float tiny = 1.17549435e-38f;
            float u = fmaxf(tiny, __fadd_rn(__fmul_rn(f, 1.0f), tiny));
            gmb[c] = -logf(-logf(u));
        }
        int best = 0;
        float bz = gmb[0] + lg[0];
#pragma unroll
        for (int c = 1; c < 4; ++c) {
            float z = gmb[c] + lg[c];
            if (z > bz) { bz = z; best = c; }
        }
        float M = fmaxf(fmaxf(lg[0], lg[1]), fmaxf(lg[2], lg[3]));
        float se = 0.f;
#pragma unroll
        for (int c = 0; c < 4; ++c) se += expf(lg[c] - M);
        float lse = M + logf(se);
        float ent = 0.f;
#pragma unroll
        for (int c = 0; c < 4; ++c) {
            float lp = lg[c] - lse;
            ent -= expf(lp) * lp;
        }
        ob[512 + g] = (float)best;
        ob[1536 + g] = lg[best] - lse;
        ob[2560 + g] = ent;
        ob[3072 + g] = lcv;
        ob[3584 + g] = mcv_sh;
    }
}

// ---------------- launch ----------------
extern "C" void kernel_launch(void* const* d_in, const int* in_sizes, int n_in,
                              void* d_out, int out_size, void* d_ws, size_t ws_size,
                              hipStream_t stream) {
    const float* x   = (const float*)d_in[0];
    const int* ei    = (const int*)d_in[1];
    const float* ea  = (const float*)d_in[2];
    const float* We0 = (const float*)d_in[5];
    const float* be0 = (const float*)d_in[6];
    const float* W0  = (const float*)d_in[7];
    const float* b0  = (const float*)d_in[8];
    const float* We1 = (const float*)d_in[9];
    const float* be1 = (const float*)d_in[10];
    const float* W1  = (const float*)d_in[11];
    const float* b1  = (const float*)d_in[12];
    const float* We2 = (const float*)d_in[13];
    const float* be2 = (const float*)d_in[14];
    const float* W2  = (const float*)d_in[15];
    const float* b2  = (const float*)d_in[16];
    const float* laW1 = (const float*)d_in[17];
    const float* lab1 = (const float*)d_in[18];
    const float* laW2 = (const float*)d_in[19];
    const float* lab2 = (const float*)d_in[20];
    const float* maW1 = (const float*)d_in[21];
    const float* mab1 = (const float*)d_in[22];
    const float* maW2 = (const float*)d_in[23];
    const float* mab2 = (const float*)d_in[24];
    const float* lcW1 = (const float*)d_in[25];
    const float* lcb1 = (const float*)d_in[26];
    const float* lcW2 = (const float*)d_in[27];
    const float* lcb2 = (const float*)d_in[28];
    const float* mcW1 = (const float*)d_in[29];
    const float* mcb1 = (const float*)d_in[30];
    const float* mcW2 = (const float*)d_in[31];
    const float* mcb2 = (const float*)d_in[32];

    float* out = (float*)d_out;
    char* ws = (char*)d_ws;
    size_t off = 0;
    auto alloc = [&](size_t bytes) -> void* {
        void* p = ws + off;
        off += (bytes + 255) & ~(size_t)255;
        return p;
    };
    float* U    = (float*)alloc((size_t)NN * 128 * 4);  // 128 MB ping-pong
    int* counts = (int*)alloc((size_t)NN * 4);
    int* offs   = (int*)alloc((size_t)(NN + 1) * 4);
    int* cursor = (int*)alloc((size_t)NN * 4);
    int* ssrc   = (int*)alloc((size_t)EE * 4);
    float4* sea = (float4*)alloc((size_t)EE * 16);
    int* bsum   = (int*)alloc(512 * 4);
    int* bbase  = (int*)alloc(512 * 4);
    int* bscr   = (int*)alloc(512 * 4);
    float* Lg   = (float*)alloc((size_t)NN * 4);
    float* pooled = (float*)alloc((size_t)BB * 128 * 4);
    int* locInt = (int*)alloc((size_t)BB * 4);

    const int* src = ei;
    const int* dstA = ei + EE;
    float* V = out + 4096;
    float* agg0 = U;

    hipMemsetAsync(counts, 0, (size_t)NN * 4, stream);
    csr_count<<<EE / 256, 256, 0, stream>>>(dstA, counts, EE);
    scan512<<<NN / 512, 512, 0, stream>>>(counts, offs, bsum);
    scan512<<<1, 512, 0, stream>>>(bsum, bbase, bscr);
    scan_fix<<<NN / 512, 512, 0, stream>>>(offs, bbase, cursor, NN, EE);
    csr_fill<<<EE / 256, 256, 0, stream>>>(dstA, src, (const float4*)ea, cursor, ssrc, sea, EE);

    agg_l0<<<NN / 256, 256, 0, stream>>>(x, ssrc, sea, offs, We0, be0, agg0);
    update_l0<<<NN / 2, 256, 0, stream>>>(x, agg0, W0, b0, V);
    agg_l<<<NN / 4, 256, 0, stream>>>((const float2*)V, ssrc, sea, offs, We1, be1, (float2*)U);
    gemm_k<<<NN / 128, 256, 0, stream>>>(V, U, W1, b1, U);
    agg_l<<<NN / 4, 256, 0, stream>>>((const float2*)U, ssrc, sea, offs, We2, be2, (float2*)V);
    gemm_k<<<NN / 128, 256, 0, stream>>>(U, V, W2, b2, V);

    gemm_logit<<<NN / 128, 256, 0, stream>>>(V, laW1, lab1, laW2, lab2, Lg);
    sample_k<<<BB, 256, 0, stream>>>(Lg, out, locInt);

    pool_k<<<BB, 512, 0, stream>>>(V, pooled);
    heads_k<<<BB, 128, 0, stream>>>(V, pooled, locInt, maW1, mab1, maW2, mab2,
                                    lcW1, lcb1, lcW2, lcb2, mcW1, mcb1, mcW2, mcb2, out);
}